// Round 8
// baseline (33.928 us; speedup 1.0000x reference)
//
#include <hip/hip_runtime.h>

#define NUM_CLASS 121
#define BROWS 262144
#define THREADS 256
#define BLOCKS (BROWS / THREADS)           // 1024 (power of 2: 2^32 % 1024 == 0)
#define TOTAL (BROWS * NUM_CLASS)          // 31719424 < 2^31

// Single kernel, rocPRIM-style "last block finishes" reduction.
//  - one thread per row; 5 taps of row r lie in the aligned 8-float window at
//    ga = clamp((r*121+lab-2)&~3, 0, TOTAL-8): two float4 loads (minimal lines)
//  - block reduce -> partial[blockIdx], release fence, ticket atomicAdd
//  - ticket old & 1023 == 1023 triggers the finishing block. Because 2^32 is
//    divisible by 1024, ANY initial counter value (0xAA poison included) and
//    counter wrap produce exactly one trigger per call -> no memset needed,
//    and the counter needs no reset between graph replays.
__global__ __launch_bounds__(THREADS)
void sce_fused(const float* __restrict__ pred,
               const int*   __restrict__ label,
               const float* __restrict__ kw,
               float*        partial,          // d_ws[0..1023]
               unsigned int* counter,          // d_ws + 4096 B (own cache line)
               float*        out) {
    const int row = blockIdx.x * THREADS + threadIdx.x;   // grid covers BROWS exactly

    const float w0 = kw[0], w1 = kw[1], w2 = kw[2], w3 = kw[3], w4 = kw[4];

    const int lab  = label[row];
    const int base = row * NUM_CLASS;
    const int g    = base + lab - 2;       // flat index of tap j=0
    int ga = g & ~3;                       // 16B-aligned window start
    ga = ga < 0 ? 0 : ga;
    ga = ga > (TOTAL - 8) ? (TOTAL - 8) : ga;

    const float4 q0 = *reinterpret_cast<const float4*>(pred + ga);
    const float4 q1 = *reinterpret_cast<const float4*>(pred + ga + 4);
    const float v[8] = {q0.x, q0.y, q0.z, q0.w, q1.x, q1.y, q1.z, q1.w};

    float acc = 0.0f;
    #pragma unroll
    for (int i = 0; i < 8; ++i) {
        const int j = (ga - g) + i;        // tap index; valid taps are 0..4
        const int c = (ga - base) + i;     // class index of this window slot
        const bool ok = (j >= 0) & (j < 5) & (c >= 0) & (c < NUM_CLASS);
        float wj = (j <= 0) ? w0 : (j == 1) ? w1 : (j == 2) ? w2
                 : (j == 3) ? w3 : w4;
        wj = ok ? wj : 0.0f;
        acc -= wj * __logf(v[i] + 1e-8f);  // v_log_f32 (validated R3-R7)
    }

    // wave-64 butterfly reduce
    #pragma unroll
    for (int off = 32; off > 0; off >>= 1)
        acc += __shfl_down(acc, off, 64);

    __shared__ float wsum[THREADS / 64];
    const int lane = threadIdx.x & 63;
    const int wid  = threadIdx.x >> 6;
    if (lane == 0) wsum[wid] = acc;
    __syncthreads();

    __shared__ bool amLast;
    if (threadIdx.x == 0) {
        partial[blockIdx.x] = wsum[0] + wsum[1] + wsum[2] + wsum[3];
        __threadfence();                           // release: partial visible device-wide
        const unsigned int old = atomicAdd(counter, 1u);   // device-scope ticket
        amLast = ((old & (BLOCKS - 1u)) == (BLOCKS - 1u));
    }
    __syncthreads();

    if (amLast) {
        __threadfence();                           // acquire: no stale L1 for partial[]
        volatile const float* vp = partial;        // defeat register caching
        float a = vp[threadIdx.x]
                + vp[threadIdx.x + 256]
                + vp[threadIdx.x + 512]
                + vp[threadIdx.x + 768];           // fixed order -> deterministic

        #pragma unroll
        for (int off = 32; off > 0; off >>= 1)
            a += __shfl_down(a, off, 64);

        __shared__ float wsum2[THREADS / 64];
        if (lane == 0) wsum2[wid] = a;
        __syncthreads();

        if (threadIdx.x == 0) {
            const float s = wsum2[0] + wsum2[1] + wsum2[2] + wsum2[3];
            out[0] = s * (1.0f / ((float)BROWS * (float)NUM_CLASS));
        }
    }
}

extern "C" void kernel_launch(void* const* d_in, const int* in_sizes, int n_in,
                              void* d_out, int out_size, void* d_ws, size_t ws_size,
                              hipStream_t stream) {
    const float* pred  = (const float*)d_in[0];
    const int*   label = (const int*)d_in[1];
    const float* kw    = (const float*)d_in[2];
    float*       out   = (float*)d_out;
    float*       part  = (float*)d_ws;                          // 4 KiB
    unsigned int* cnt  = (unsigned int*)((char*)d_ws + 4096);   // own cache line

    sce_fused<<<BLOCKS, THREADS, 0, stream>>>(pred, label, kw, part, cnt, out);
}

// Round 9
// 12.367 us; speedup vs baseline: 2.7434x; 2.7434x over previous
//
#include <hip/hip_runtime.h>

#define NUM_CLASS 121
#define BROWS 262144
#define THREADS 256
#define BLOCKS (BROWS / THREADS)          // 1024
#define TOTAL (BROWS * NUM_CLASS)          // 31719424 < 2^31

// Kernel 1 (session-best config, R7): one thread per row.
// The 5 taps pred[row, lab-2..lab+2] (clipped) always lie in the 8-float
// aligned window at ga = clamp((row*121+lab-2)&~3, 0, TOTAL-8). Two float4
// loads per row (exactly the cache lines the taps touch), predicated weights
// per window slot, fast log (validated absmax 0.0 across R3-R8).
// Cross-XCD sync lessons: grid-sync = +127us (R3), fence+atomic ticket
// = +21us (R8) -> a second 1.3us dispatch is the cheapest global barrier.
__global__ __launch_bounds__(THREADS)
void sce_partial(const float* __restrict__ pred,
                 const int*   __restrict__ label,
                 const float* __restrict__ kw,
                 float*       __restrict__ partial) {
    const int row = blockIdx.x * THREADS + threadIdx.x;   // grid covers BROWS exactly

    const float w0 = kw[0], w1 = kw[1], w2 = kw[2], w3 = kw[3], w4 = kw[4];

    const int lab  = label[row];
    const int base = row * NUM_CLASS;
    const int g    = base + lab - 2;       // flat index of tap j=0
    int ga = g & ~3;                       // 16B-aligned window start
    ga = ga < 0 ? 0 : ga;
    ga = ga > (TOTAL - 8) ? (TOTAL - 8) : ga;

    const float4 q0 = *reinterpret_cast<const float4*>(pred + ga);
    const float4 q1 = *reinterpret_cast<const float4*>(pred + ga + 4);
    const float v[8] = {q0.x, q0.y, q0.z, q0.w, q1.x, q1.y, q1.z, q1.w};

    float acc = 0.0f;
    #pragma unroll
    for (int i = 0; i < 8; ++i) {
        const int j = (ga - g) + i;        // tap index; valid taps are 0..4
        const int c = (ga - base) + i;     // class index of this window slot
        const bool ok = (j >= 0) & (j < 5) & (c >= 0) & (c < NUM_CLASS);
        float wj = (j <= 0) ? w0 : (j == 1) ? w1 : (j == 2) ? w2
                 : (j == 3) ? w3 : w4;
        wj = ok ? wj : 0.0f;
        acc -= wj * __logf(v[i] + 1e-8f);
    }

    #pragma unroll
    for (int off = 32; off > 0; off >>= 1)
        acc += __shfl_down(acc, off, 64);

    __shared__ float wsum[THREADS / 64];
    const int lane = threadIdx.x & 63;
    const int wid  = threadIdx.x >> 6;
    if (lane == 0) wsum[wid] = acc;
    __syncthreads();

    if (threadIdx.x == 0)
        partial[blockIdx.x] = wsum[0] + wsum[1] + wsum[2] + wsum[3];
}

// Kernel 2: single block, 256 threads, ONE float4 per thread covers all
// 1024 partials in a single VMEM instruction -> one memory round-trip,
// then shuffle+LDS reduce and the scaled scalar store.
__global__ __launch_bounds__(THREADS)
void sce_reduce(const float* __restrict__ partial,
                float*       __restrict__ out) {
    const float4 q = reinterpret_cast<const float4*>(partial)[threadIdx.x];
    float acc = (q.x + q.y) + (q.z + q.w);

    #pragma unroll
    for (int off = 32; off > 0; off >>= 1)
        acc += __shfl_down(acc, off, 64);

    __shared__ float wsum[THREADS / 64];
    const int lane = threadIdx.x & 63;
    const int wid  = threadIdx.x >> 6;
    if (lane == 0) wsum[wid] = acc;
    __syncthreads();

    if (threadIdx.x == 0) {
        const float s = wsum[0] + wsum[1] + wsum[2] + wsum[3];
        out[0] = s * (1.0f / ((float)BROWS * (float)NUM_CLASS));
    }
}

extern "C" void kernel_launch(void* const* d_in, const int* in_sizes, int n_in,
                              void* d_out, int out_size, void* d_ws, size_t ws_size,
                              hipStream_t stream) {
    const float* pred  = (const float*)d_in[0];
    const int*   label = (const int*)d_in[1];
    const float* kw    = (const float*)d_in[2];
    float*       out   = (float*)d_out;
    float*       part  = (float*)d_ws;       // 1024 floats = 4 KiB scratch

    sce_partial<<<BLOCKS, THREADS, 0, stream>>>(pred, label, kw, part);
    sce_reduce<<<1, THREADS, 0, stream>>>(part, out);
}